// Round 4
// baseline (89.760 us; speedup 1.0000x reference)
//
#include <hip/hip_runtime.h>
#include <cstdint>

static constexpr int BATCH = 64;
static constexpr int NPB   = 512 * 512;   // elements per batch
static constexpr int NCB   = 1024;        // 512 half-bins x 2 target classes
static constexpr int HBLK  = 16;          // hist blocks per batch

// d_ws layout in 32-bit words:
static constexpr int W_BMIN  = 0;      // 1024 floats: per-block min
static constexpr int W_BMAX  = 1024;   // 1024 floats: per-block max
static constexpr int W_CNT1  = 2048;   // 64 uint: per-batch arrival tickets
static constexpr int W_CNT2  = 2112;   // 1 uint: leader ticket
static constexpr int W_IOU   = 2176;   // 64 floats: per-batch IoU
static constexpr int W_HPART = 4096;   // 1024*1024 uint partial hists (4 MiB), 16B aligned
static constexpr int W_END   = W_HPART + BATCH * HBLK * NCB;

__device__ __forceinline__ float sigmoidf(float v) {   // precise: pmin/pmax/centers only
  if (v >= 0.0f) return 1.0f / (1.0f + expf(-v));
  float e = expf(v);
  return e / (1.0f + e);
}
__device__ __forceinline__ float fsig(float v) {       // fast: per-element binning only
  return __builtin_amdgcn_rcpf(1.0f + __expf(-v));
}

// K1: 16 blocks per batch — per-block min/max of raw logits; block 0 zeroes tickets.
__global__ __launch_bounds__(256) void k_pass1(const float* __restrict__ x,
                                               uint32_t* __restrict__ ws) {
  const int g = blockIdx.x;
  const int t = threadIdx.x;
  if (g == 0 && t < 65) ws[W_CNT1 + t] = 0u;   // cnt1[64] + cnt2
  const int b = g >> 4;
  const int blk = g & 15;
  const float4* p = reinterpret_cast<const float4*>(x + (size_t)b * NPB + (size_t)blk * (NPB / 16));
  float mn = INFINITY, mx = -INFINITY;
#pragma unroll
  for (int i = 0; i < 16; ++i) {
    float4 v = p[i * 256 + t];
    mn = fminf(mn, fminf(fminf(v.x, v.y), fminf(v.z, v.w)));
    mx = fmaxf(mx, fmaxf(fmaxf(v.x, v.y), fmaxf(v.z, v.w)));
  }
  for (int off = 32; off; off >>= 1) {
    mn = fminf(mn, __shfl_down(mn, off));
    mx = fmaxf(mx, __shfl_down(mx, off));
  }
  __shared__ float smn[4], smx[4];
  if ((t & 63) == 0) { smn[t >> 6] = mn; smx[t >> 6] = mx; }
  __syncthreads();
  if (t == 0) {
    float* wsf = reinterpret_cast<float*>(ws);
    wsf[W_BMIN + g] = fminf(fminf(smn[0], smn[1]), fminf(smn[2], smn[3]));
    wsf[W_BMAX + g] = fmaxf(fmaxf(smx[0], smx[1]), fmaxf(smx[2], smx[3]));
  }
}

// K2: hist (all 1024 blocks) -> per-batch leader does Otsu+IoU -> last leader writes mean.
__global__ __launch_bounds__(256) void k_main(const float* __restrict__ x,
                                              const float* __restrict__ tg,
                                              uint32_t* __restrict__ ws,
                                              float* __restrict__ out) {
  __shared__ uint32_t h[4 * NCB];        // 16 KiB: wave-replica hists, later Otsu scratch
  __shared__ float sPmin, sScale, sBinw;
  __shared__ int sFlag;
  const int t = threadIdx.x;
  const int g = blockIdx.x;
  const int b = g >> 4;
  const int blk = g & 15;
  const float* wsf = reinterpret_cast<const float*>(ws);
  float* wsfw = reinterpret_cast<float*>(ws);

  // per-batch min/max reduce (redundant per block; 16 L2-hot loads)
  float mnv = (t < 16) ? wsf[W_BMIN + (b << 4) + t] : INFINITY;
  float mxv = (t < 16) ? wsf[W_BMAX + (b << 4) + t] : -INFINITY;
  for (int off = 8; off; off >>= 1) {
    mnv = fminf(mnv, __shfl_down(mnv, off));
    mxv = fmaxf(mxv, __shfl_down(mxv, off));
  }
  if (t == 0) {
    const float pmin = sigmoidf(mnv);
    const float pmax = sigmoidf(mxv);
    const float span = pmax - pmin;
    sPmin = pmin;
    sScale = (span > 0.0f) ? (512.0f / span) : 0.0f;   // == 2*(256/span) bit-exactly
    sBinw = span * (1.0f / 256.0f);                    // span/NBINS (pow2, exact)
  }
  const uint4 z = {0u, 0u, 0u, 0u};
  reinterpret_cast<uint4*>(h)[t]       = z;
  reinterpret_cast<uint4*>(h)[t + 256] = z;
  reinterpret_cast<uint4*>(h)[t + 512] = z;
  reinterpret_cast<uint4*>(h)[t + 768] = z;
  __syncthreads();

  // ---- histogram this block's slice ----
  const float pmin = sPmin, scale = sScale;
  const uint32_t woff = (uint32_t)(t >> 6) << 10;   // wave-replica base
  const size_t base = (size_t)b * NPB + (size_t)blk * (NPB / 16);
  const float4* px = reinterpret_cast<const float4*>(x + base);
  const float4* pt = reinterpret_cast<const float4*>(tg + base);
#pragma unroll 4
  for (int i = 0; i < 16; ++i) {
    float4 v = px[i * 256 + t];
    float4 w = pt[i * 256 + t];
#define PUT(a, c) { float fv = (fsig(a) - pmin) * scale;                  \
                    int idx = (int)fv;                                     \
                    idx = idx < 0 ? 0 : (idx > 511 ? 511 : idx);           \
                    idx += ((c) > 0.5f) ? 512 : 0;                         \
                    atomicAdd(&h[woff + idx], 1u); }
    PUT(v.x, w.x) PUT(v.y, w.y) PUT(v.z, w.z) PUT(v.w, w.w)
#undef PUT
  }
  __syncthreads();
  // merge 4 replicas -> this block's global partial slot (coalesced stores)
  uint32_t* gp = ws + W_HPART + (size_t)g * NCB;
#pragma unroll
  for (int j = 0; j < 4; ++j) {
    const int i = t + j * 256;
    gp[i] = h[i] + h[i + 1024] + h[i + 2048] + h[i + 3072];
  }
  __syncthreads();                       // all partial stores issued block-wide
  if (t == 0) {
    __threadfence();                     // make them device-visible
    const uint32_t old = atomicAdd(&ws[W_CNT1 + b], 1u);
    sFlag = (old == HBLK - 1);
  }
  __syncthreads();
  if (!sFlag) return;                    // non-leader blocks done
  __threadfence();                       // acquire: peers' partials now visible

  // ---- Otsu + IoU (one leader block per batch) ----
  uint32_t* hc  = h;                                    // 1024
  uint32_t* w1s = h + 1024;                             // 256
  float*    s1s = reinterpret_cast<float*>(h + 1280);   // 256
  float*    vv  = reinterpret_cast<float*>(h + 1536);   // 256
  int*      vi  = reinterpret_cast<int*>(h + 1792);     // 256
  unsigned long long* redL = reinterpret_cast<unsigned long long*>(h + 2048);  // 256 ull

  uint4 acc = {0u, 0u, 0u, 0u};
#pragma unroll
  for (int p = 0; p < HBLK; ++p) {
    const uint4 v = reinterpret_cast<const uint4*>(ws + W_HPART + (size_t)((b << 4) + p) * NCB)[t];
    acc.x += v.x; acc.y += v.y; acc.z += v.z; acc.w += v.w;
  }
  reinterpret_cast<uint4*>(hc)[t] = acc;
  __syncthreads();
  const float binw = sBinw;
  const uint32_t a0 = hc[2 * t] + hc[2 * t + 512];
  const uint32_t a1 = hc[2 * t + 1] + hc[2 * t + 513];
  const uint32_t p0 = hc[2 * t + 512], p1 = hc[2 * t + 513];
  const uint32_t hk = a0 + a1;                        // reference 256-bin hist[t]
  const float ck = pmin + ((float)t + 0.5f) * binw;   // centers[t]
  w1s[t] = hk;
  s1s[t] = (float)hk * ck;
  for (int off = 1; off < 256; off <<= 1) {           // Hillis-Steele scans (w1 exact)
    __syncthreads();
    uint32_t wp = (t >= off) ? w1s[t - off] : 0u;
    float    sp = (t >= off) ? s1s[t - off] : 0.0f;
    __syncthreads();
    w1s[t] += wp; s1s[t] += sp;
  }
  __syncthreads();
  const uint32_t totW = w1s[255];
  const float totS = s1s[255];
  float v = -INFINITY;
  if (t < 255) {
    const float w1f = (float)w1s[t];
    const float w2f = (float)(totW - w1s[t]);
    const float m1 = s1s[t] / w1f;
    const float m2 = (totS - s1s[t]) / w2f;
    const float d = m1 - m2;
    v = (w1f * w2f) * (d * d);
  }
  vv[t] = v; vi[t] = t;
  for (int s = 128; s; s >>= 1) {        // argmax, first-occurrence tie-break
    __syncthreads();
    if (t < s) {
      const float vb = vv[t + s]; const int ib = vi[t + s];
      if (vb > vv[t] || (vb == vv[t] && ib < vi[t])) { vv[t] = vb; vi[t] = ib; }
    }
  }
  __syncthreads();
  const int J = 2 * vi[0] + 1;           // threshold = half-bin boundary index
  const uint32_t nb_p = ((2 * t) >= J ? a0 : 0u) + ((2 * t + 1) >= J ? a1 : 0u);
  const uint32_t ni_p = ((2 * t) >= J ? p0 : 0u) + ((2 * t + 1) >= J ? p1 : 0u);
  const uint32_t nt_p = p0 + p1;
  redL[t] = (unsigned long long)nb_p | ((unsigned long long)ni_p << 20) | ((unsigned long long)nt_p << 40);
  for (int s = 128; s; s >>= 1) {
    __syncthreads();
    if (t < s) redL[t] += redL[t + s];
  }
  __syncthreads();
  if (t == 0) {
    const unsigned long long P = redL[0];
    const float nb = (float)(uint32_t)(P & 0xFFFFFu);
    const float ni = (float)(uint32_t)((P >> 20) & 0xFFFFFu);
    const float nt = (float)(uint32_t)((P >> 40) & 0xFFFFFu);
    const float uni = nb + nt - ni;
    wsfw[W_IOU + b] = (ni + 1.0f) / (uni + 1.0f);
    __threadfence();
    const uint32_t old = atomicAdd(&ws[W_CNT2], 1u);
    sFlag = (old == BATCH - 1);
  }
  __syncthreads();
  if (!sFlag) return;                    // all but the last leader done
  __threadfence();                       // acquire: all 64 IoUs visible

  // ---- final mean (single wave of the last leader) ----
  if (t < 64) {
    float iou = wsf[W_IOU + t];
    for (int off = 32; off; off >>= 1) iou += __shfl_down(iou, off);
    if (t == 0) out[0] = iou * (1.0f / 64.0f);
  }
}

extern "C" void kernel_launch(void* const* d_in, const int* in_sizes, int n_in,
                              void* d_out, int out_size, void* d_ws, size_t ws_size,
                              hipStream_t stream) {
  const float* x  = (const float*)d_in[0];   // logits (64,1,512,512)
  const float* tg = (const float*)d_in[1];   // target (64,1,512,512)
  uint32_t* ws = (uint32_t*)d_ws;
  float* out = (float*)d_out;

  hipLaunchKernelGGL(k_pass1, dim3(BATCH * HBLK), dim3(256), 0, stream, x, ws);
  hipLaunchKernelGGL(k_main,  dim3(BATCH * HBLK), dim3(256), 0, stream, x, tg, ws, out);
}

// Round 5
// 44.574 us; speedup vs baseline: 2.0137x; 2.0137x over previous
//
#include <hip/hip_runtime.h>
#include <cstdint>

static constexpr int BATCH = 64;
static constexpr int NPB   = 512 * 512;   // elements per batch
static constexpr int NCB   = 1024;        // 512 half-bins x 2 target classes
static constexpr int HBLK  = 16;          // hist blocks per batch

// d_ws layout in 32-bit words:
static constexpr int W_BMIN = 0;      // 1024 floats: per-block min
static constexpr int W_BMAX = 1024;   // 1024 floats: per-block max
static constexpr int W_CNT  = 2048;   // 64 uint: per-batch arrival tickets
static constexpr int W_GH   = 4096;   // 64*1024 uint: per-batch global hists (zeroed in k_pass1)

__device__ __forceinline__ float sigmoidf(float v) {   // precise: pmin/pmax/centers only
  if (v >= 0.0f) return 1.0f / (1.0f + expf(-v));
  float e = expf(v);
  return e / (1.0f + e);
}
__device__ __forceinline__ float fsig(float v) {       // fast: per-element binning only
  return __builtin_amdgcn_rcpf(1.0f + __expf(-v));
}

// K1: 16 blocks/batch — per-block min/max of raw logits; also zero hist/tickets/out.
__global__ __launch_bounds__(256) void k_pass1(const float* __restrict__ x,
                                               uint32_t* __restrict__ ws,
                                               float* __restrict__ out) {
  const int g = blockIdx.x;
  const int t = threadIdx.x;
  // zero this launch's accumulators (plain stores; flushed at kernel boundary)
  if (t < 64) ws[W_GH + g * 64 + t] = 0u;          // 1024 blocks x 64 words = whole hist zone
  if (g == 0 && t < 64) ws[W_CNT + t] = 0u;
  if (g == 0 && t == 0) out[0] = 0.0f;
  const int b = g >> 4;
  const int blk = g & 15;
  const float4* p = reinterpret_cast<const float4*>(x + (size_t)b * NPB + (size_t)blk * (NPB / 16));
  float mn = INFINITY, mx = -INFINITY;
#pragma unroll
  for (int i = 0; i < 16; ++i) {
    float4 v = p[i * 256 + t];
    mn = fminf(mn, fminf(fminf(v.x, v.y), fminf(v.z, v.w)));
    mx = fmaxf(mx, fmaxf(fmaxf(v.x, v.y), fmaxf(v.z, v.w)));
  }
  for (int off = 32; off; off >>= 1) {
    mn = fminf(mn, __shfl_down(mn, off));
    mx = fmaxf(mx, __shfl_down(mx, off));
  }
  __shared__ float smn[4], smx[4];
  if ((t & 63) == 0) { smn[t >> 6] = mn; smx[t >> 6] = mx; }
  __syncthreads();
  if (t == 0) {
    float* wsf = reinterpret_cast<float*>(ws);
    wsf[W_BMIN + g] = fminf(fminf(smn[0], smn[1]), fminf(smn[2], smn[3]));
    wsf[W_BMAX + g] = fmaxf(fmaxf(smx[0], smx[1]), fmaxf(smx[2], smx[3]));
  }
}

// K2: hist via LDS replicas -> device atomicAdd into per-batch hist (at LLC, no fences)
//     -> last-arriver leader per batch does Otsu+IoU -> atomicAdd of iou/64 into out[0].
__global__ __launch_bounds__(256) void k_main(const float* __restrict__ x,
                                              const float* __restrict__ tg,
                                              uint32_t* __restrict__ ws,
                                              float* __restrict__ out) {
  __shared__ uint32_t h[4 * NCB];        // 16 KiB: wave-replica hists, later Otsu scratch
  __shared__ float sPmin, sScale, sBinw;
  __shared__ int sFlag;
  const int t = threadIdx.x;
  const int g = blockIdx.x;
  const int b = g >> 4;
  const int blk = g & 15;
  const float* wsf = reinterpret_cast<const float*>(ws);

  // per-batch min/max reduce (16 loads, L2-hot; written by previous kernel)
  float mnv = (t < 16) ? wsf[W_BMIN + (b << 4) + t] : INFINITY;
  float mxv = (t < 16) ? wsf[W_BMAX + (b << 4) + t] : -INFINITY;
  for (int off = 8; off; off >>= 1) {
    mnv = fminf(mnv, __shfl_down(mnv, off));
    mxv = fmaxf(mxv, __shfl_down(mxv, off));
  }
  if (t == 0) {
    const float pmin = sigmoidf(mnv);
    const float pmax = sigmoidf(mxv);
    const float span = pmax - pmin;
    sPmin = pmin;
    sScale = (span > 0.0f) ? (512.0f / span) : 0.0f;   // == 2*(256/span) bit-exactly
    sBinw = span * (1.0f / 256.0f);                    // span/NBINS (pow2, exact)
  }
  const uint4 z = {0u, 0u, 0u, 0u};
  reinterpret_cast<uint4*>(h)[t]       = z;
  reinterpret_cast<uint4*>(h)[t + 256] = z;
  reinterpret_cast<uint4*>(h)[t + 512] = z;
  reinterpret_cast<uint4*>(h)[t + 768] = z;
  __syncthreads();

  // ---- histogram this block's slice into per-wave LDS replicas ----
  const float pmin = sPmin, scale = sScale;
  const uint32_t woff = (uint32_t)(t >> 6) << 10;
  const size_t base = (size_t)b * NPB + (size_t)blk * (NPB / 16);
  const float4* px = reinterpret_cast<const float4*>(x + base);
  const float4* pt = reinterpret_cast<const float4*>(tg + base);
#pragma unroll 4
  for (int i = 0; i < 16; ++i) {
    float4 v = px[i * 256 + t];
    float4 w = pt[i * 256 + t];
#define PUT(a, c) { float fv = (fsig(a) - pmin) * scale;                  \
                    int idx = (int)fv;                                     \
                    idx = idx < 0 ? 0 : (idx > 511 ? 511 : idx);           \
                    idx += ((c) > 0.5f) ? 512 : 0;                         \
                    atomicAdd(&h[woff + idx], 1u); }
    PUT(v.x, w.x) PUT(v.y, w.y) PUT(v.z, w.z) PUT(v.w, w.w)
#undef PUT
  }
  __syncthreads();
  // merge replicas -> per-batch global hist via device atomics (performed at LLC)
  uint32_t* gh = ws + W_GH + (size_t)b * NCB;
#pragma unroll
  for (int j = 0; j < 4; ++j) {
    const int i = t + j * 256;
    const uint32_t v = h[i] + h[i + 1024] + h[i + 2048] + h[i + 3072];
    if (v) atomicAdd(&gh[i], v);
  }
  __syncthreads();                       // drains vmcnt(0): hist atomics complete at LLC
  if (t == 0) {
    const uint32_t old = atomicAdd(&ws[W_CNT + b], 1u);   // relaxed ticket, no fence
    sFlag = (old == HBLK - 1);
  }
  __syncthreads();
  if (!sFlag) return;                    // non-leader blocks done

  // ---- Otsu + IoU (the last-arriving block per batch) ----
  uint32_t* hc  = h;                                    // 1024
  uint32_t* w1s = h + 1024;                             // 256
  float*    s1s = reinterpret_cast<float*>(h + 1280);   // 256
  float*    vv  = reinterpret_cast<float*>(h + 1536);   // 256
  int*      vi  = reinterpret_cast<int*>(h + 1792);     // 256
  unsigned long long* redL = reinterpret_cast<unsigned long long*>(h + 2048);  // 256 ull

  // agent-scope atomic loads: bypass local L1/L2, read the LLC-resident bin values
#pragma unroll
  for (int j = 0; j < 4; ++j) {
    const int i = t + j * 256;
    hc[i] = __hip_atomic_load(&gh[i], __ATOMIC_RELAXED, __HIP_MEMORY_SCOPE_AGENT);
  }
  __syncthreads();
  const float binw = sBinw;
  const uint32_t a0 = hc[2 * t] + hc[2 * t + 512];
  const uint32_t a1 = hc[2 * t + 1] + hc[2 * t + 513];
  const uint32_t p0 = hc[2 * t + 512], p1 = hc[2 * t + 513];
  const uint32_t hk = a0 + a1;                        // reference 256-bin hist[t]
  const float ck = pmin + ((float)t + 0.5f) * binw;   // centers[t]
  w1s[t] = hk;
  s1s[t] = (float)hk * ck;
  for (int off = 1; off < 256; off <<= 1) {           // Hillis-Steele scans (w1 exact)
    __syncthreads();
    uint32_t wp = (t >= off) ? w1s[t - off] : 0u;
    float    sp = (t >= off) ? s1s[t - off] : 0.0f;
    __syncthreads();
    w1s[t] += wp; s1s[t] += sp;
  }
  __syncthreads();
  const uint32_t totW = w1s[255];
  const float totS = s1s[255];
  float v = -INFINITY;
  if (t < 255) {
    const float w1f = (float)w1s[t];
    const float w2f = (float)(totW - w1s[t]);
    const float m1 = s1s[t] / w1f;
    const float m2 = (totS - s1s[t]) / w2f;
    const float d = m1 - m2;
    v = (w1f * w2f) * (d * d);
  }
  vv[t] = v; vi[t] = t;
  for (int s = 128; s; s >>= 1) {        // argmax, first-occurrence tie-break
    __syncthreads();
    if (t < s) {
      const float vb = vv[t + s]; const int ib = vi[t + s];
      if (vb > vv[t] || (vb == vv[t] && ib < vi[t])) { vv[t] = vb; vi[t] = ib; }
    }
  }
  __syncthreads();
  const int J = 2 * vi[0] + 1;           // threshold = half-bin boundary index
  const uint32_t nb_p = ((2 * t) >= J ? a0 : 0u) + ((2 * t + 1) >= J ? a1 : 0u);
  const uint32_t ni_p = ((2 * t) >= J ? p0 : 0u) + ((2 * t + 1) >= J ? p1 : 0u);
  const uint32_t nt_p = p0 + p1;
  redL[t] = (unsigned long long)nb_p | ((unsigned long long)ni_p << 20) | ((unsigned long long)nt_p << 40);
  for (int s = 128; s; s >>= 1) {
    __syncthreads();
    if (t < s) redL[t] += redL[t + s];
  }
  __syncthreads();
  if (t == 0) {
    const unsigned long long P = redL[0];
    const float nb = (float)(uint32_t)(P & 0xFFFFFu);
    const float ni = (float)(uint32_t)((P >> 20) & 0xFFFFFu);
    const float nt = (float)(uint32_t)((P >> 40) & 0xFFFFFu);
    const float uni = nb + nt - ni;
    const float iou = (ni + 1.0f) / (uni + 1.0f);
    atomicAdd(out, iou * (1.0f / 64.0f));   // device-scope fp add into zeroed out[0]
  }
}

extern "C" void kernel_launch(void* const* d_in, const int* in_sizes, int n_in,
                              void* d_out, int out_size, void* d_ws, size_t ws_size,
                              hipStream_t stream) {
  const float* x  = (const float*)d_in[0];   // logits (64,1,512,512)
  const float* tg = (const float*)d_in[1];   // target (64,1,512,512)
  uint32_t* ws = (uint32_t*)d_ws;
  float* out = (float*)d_out;

  hipLaunchKernelGGL(k_pass1, dim3(BATCH * HBLK), dim3(256), 0, stream, x, ws, out);
  hipLaunchKernelGGL(k_main,  dim3(BATCH * HBLK), dim3(256), 0, stream, x, tg, ws, out);
}